// Round 1
// baseline (584.649 us; speedup 1.0000x reference)
//
#include <hip/hip_runtime.h>
#include <hip/hip_bf16.h>
#include <math.h>

#define NUM_EMB 32
#define ADIM 32
#define HID 1024
#define BB 128
#define TT 64

typedef __attribute__((ext_vector_type(8))) __bf16 bf16x8;
typedef __attribute__((ext_vector_type(4))) float floatx4;

// ---------------- K0: counting-sort permutation + slab worklist ------------
// perm: b-indices sorted by category.
// wl:   per 256-row slab {cat, rowstart(in perm), nvalid_b_slots, pad} (<=56 entries).
__global__ void perm_kernel(const int* __restrict__ cats, int* __restrict__ perm,
                            int* __restrict__ wl, int* __restrict__ nslab) {
  __shared__ int off[NUM_EMB];
  __shared__ int cnt[NUM_EMB];
  int tid = threadIdx.x;
  if (tid < NUM_EMB) cnt[tid] = 0;
  __syncthreads();
  if (tid < BB) atomicAdd(&cnt[cats[tid]], 1);
  __syncthreads();
  if (tid == 0) {
    int run = 0, ns = 0;
    for (int c = 0; c < NUM_EMB; ++c) {
      off[c] = run;
      int v = cnt[c];
      for (int s = 0; s < v; s += 4) {
        wl[ns * 4 + 0] = c;
        wl[ns * 4 + 1] = run + s;
        wl[ns * 4 + 2] = (v - s < 4) ? (v - s) : 4;
        wl[ns * 4 + 3] = 0;
        ++ns;
      }
      run += v;
    }
    *nslab = ns;
  }
  __syncthreads();
  if (tid < BB) {
    int pos = atomicAdd(&off[cats[tid]], 1);
    perm[pos] = tid;
  }
}

// ---------------- K1: GEMM1 (fp32, K=32) + sinusoidal tau -> x2 bf16 -------
// x2 layout: [B, T, 2048] bf16, first 1024 = a_emb, second 1024 = tau.
__global__ __launch_bounds__(256) void embed_kernel(
    const float* __restrict__ actions, const float* __restrict__ timesteps,
    const float* __restrict__ W1w, const float* __restrict__ W1b,
    const int* __restrict__ cats, __bf16* __restrict__ x2) {
  const int b = blockIdx.y;
  const int t0 = blockIdx.x * 8;
  const int cat = cats[b];
  const int tid = threadIdx.x;

  __shared__ float act[8][ADIM];
  {
    int row = tid >> 5, k = tid & 31;
    act[row][k] = actions[((size_t)(b * TT + t0 + row)) * ADIM + k];
  }
  __syncthreads();

  const float* W = W1w + (size_t)cat * ADIM * HID;
  float acc[4][8];
#pragma unroll
  for (int ii = 0; ii < 4; ++ii) {
    float bv = W1b[cat * HID + tid + ii * 256];
#pragma unroll
    for (int tt = 0; tt < 8; ++tt) acc[ii][tt] = bv;
  }
  for (int k = 0; k < ADIM; ++k) {
#pragma unroll
    for (int ii = 0; ii < 4; ++ii) {
      float w = W[k * HID + tid + ii * 256];
#pragma unroll
      for (int tt = 0; tt < 8; ++tt) acc[ii][tt] += act[tt][k] * w;
    }
  }
#pragma unroll
  for (int ii = 0; ii < 4; ++ii) {
    int hcol = tid + ii * 256;
#pragma unroll
    for (int tt = 0; tt < 8; ++tt)
      x2[((size_t)(b * TT + t0 + tt)) * 2048 + hcol] = (__bf16)acc[ii][tt];
  }
  // tau (t-independent within b; recomputed once per 8 rows)
  float tb = timesteps[b];
  const float kLog = 9.210340371976184f;  // ln(10000)
#pragma unroll
  for (int ii = 0; ii < 4; ++ii) {
    int j = tid + ii * 256;
    int jj = (j < 512) ? j : (j - 512);
    float freq = tb * expf(-kLog * (float)jj * (1.0f / 512.0f));
    float v = (j < 512) ? sinf(freq) : cosf(freq);
    __bf16 hv = (__bf16)v;
#pragma unroll
    for (int tt = 0; tt < 8; ++tt)
      x2[((size_t)(b * TT + t0 + tt)) * 2048 + 1024 + j] = hv;
  }
}

// ---------------- K2/K3: grouped bf16 MFMA GEMM (cat-grouped M=256) --------
// Block = one worklist slab (category, 4 batch elements => 256 rows) x 128 cols.
// 512 threads = 8 waves in a 4x2 grid; each wave owns 64 rows x 64 cols
// (4 mt x 4 nt 16x16 tiles, 16 MFMA per K-step, 8 ds_read_b128 per K-step).
// Weight panels are read exactly once per slab => distinct-only HBM traffic.
// LDS: As[256][40] bf16, Bs[128][40] bf16 (stride 40 keeps b128 ops bank-balanced).
template <bool SILU, bool OUT_BF16>
__global__ __launch_bounds__(512, 2) void ggemm_kernel(
    const __bf16* __restrict__ A, const float* __restrict__ Wbase,
    const float* __restrict__ bias, const int* __restrict__ perm,
    const int* __restrict__ wl, const int* __restrict__ nslab,
    void* __restrict__ Out, int K) {
  const int sid = blockIdx.y;
  if (sid >= *nslab) return;
  const int cat = wl[sid * 4 + 0];
  const int rowstart = wl[sid * 4 + 1];
  const int nvalid = wl[sid * 4 + 2];
  const int nb = blockIdx.x * 128;
  const int tid = threadIdx.x;
  const int w = tid >> 6;
  const int lane = tid & 63;
  const int q = lane >> 4;
  const int r = lane & 15;
  const int wr = w >> 1;  // 0..3 : 64-row band (== b-slot)
  const int wc = w & 1;   // 0..1 : 64-col band

  int bmap[4];
#pragma unroll
  for (int s = 0; s < 4; ++s) {
    int idx = (s < nvalid) ? s : (nvalid - 1);  // pad by duplicating last b
    bmap[s] = perm[rowstart + idx];
  }

  __shared__ __attribute__((aligned(16))) __bf16 As[256 * 40];
  __shared__ __attribute__((aligned(16))) __bf16 Bs[128 * 40];

  const float* W = Wbase + (size_t)cat * K * HID;

  // A staging: thread covers LDS rows m0 = tid>>2 and m0+128, k-chunk kc = tid&3
  const int m0 = tid >> 2;
  const int kc = tid & 3;
  const __bf16* aptr0 = A + ((size_t)bmap[m0 >> 6] * TT + (m0 & 63)) * K + kc * 8;
  const __bf16* aptr1 = A + ((size_t)bmap[(m0 >> 6) + 2] * TT + (m0 & 63)) * K + kc * 8;

  // B staging: thread covers col bn, 8 k-rows starting at kb*8
  const int bn = tid & 127;
  const int kb = tid >> 7;  // 0..3
  const float* Wp = W + (size_t)(kb * 8) * HID + nb + bn;

  floatx4 acc[4][4];
#pragma unroll
  for (int mt = 0; mt < 4; ++mt)
#pragma unroll
    for (int nt = 0; nt < 4; ++nt) acc[mt][nt] = (floatx4){0.f, 0.f, 0.f, 0.f};

  for (int k0 = 0; k0 < K; k0 += 32) {
    // global loads first (overlap previous iteration's MFMA)
    uint4 av0 = *reinterpret_cast<const uint4*>(aptr0 + k0);
    uint4 av1 = *reinterpret_cast<const uint4*>(aptr1 + k0);
    float bv[8];
#pragma unroll
    for (int j = 0; j < 8; ++j) bv[j] = Wp[(size_t)(k0 + j) * HID];

    __syncthreads();  // previous iteration's frag reads done
    *reinterpret_cast<uint4*>(&As[m0 * 40 + kc * 8]) = av0;
    *reinterpret_cast<uint4*>(&As[(m0 + 128) * 40 + kc * 8]) = av1;
    {
      union { uint4 u; __bf16 h[8]; } tb;
#pragma unroll
      for (int j = 0; j < 8; ++j) tb.h[j] = (__bf16)bv[j];
      *reinterpret_cast<uint4*>(&Bs[bn * 40 + kb * 8]) = tb.u;
    }
    __syncthreads();

    bf16x8 af[4], bfr[4];
#pragma unroll
    for (int mt = 0; mt < 4; ++mt)
      af[mt] = *reinterpret_cast<const bf16x8*>(&As[(wr * 64 + mt * 16 + r) * 40 + q * 8]);
#pragma unroll
    for (int nt = 0; nt < 4; ++nt)
      bfr[nt] = *reinterpret_cast<const bf16x8*>(&Bs[(wc * 64 + nt * 16 + r) * 40 + q * 8]);
#pragma unroll
    for (int mt = 0; mt < 4; ++mt)
#pragma unroll
      for (int nt = 0; nt < 4; ++nt)
        acc[mt][nt] = __builtin_amdgcn_mfma_f32_16x16x32_bf16(
            af[mt], bfr[nt], acc[mt][nt], 0, 0, 0);
  }

  if (wr >= nvalid) return;  // padded band: nothing to store
  const int b = bmap[wr];
  // epilogue: D row=(lane>>4)*4+reg, col=lane&15 (m89/m91-verified layout)
#pragma unroll
  for (int nt = 0; nt < 4; ++nt) {
    int col = nb + wc * 64 + nt * 16 + r;
    float bvs = bias[cat * HID + col];
#pragma unroll
    for (int mt = 0; mt < 4; ++mt) {
#pragma unroll
      for (int rr = 0; rr < 4; ++rr) {
        int trow = mt * 16 + q * 4 + rr;
        float v = acc[mt][nt][rr] + bvs;
        if (SILU) v = v / (1.0f + expf(-v));
        size_t oidx = ((size_t)b * TT + trow) * HID + col;
        if (OUT_BF16)
          ((__bf16*)Out)[oidx] = (__bf16)v;
        else
          ((float*)Out)[oidx] = v;
      }
    }
  }
}

// ---------------- launcher -------------------------------------------------
extern "C" void kernel_launch(void* const* d_in, const int* in_sizes, int n_in,
                              void* d_out, int out_size, void* d_ws, size_t ws_size,
                              hipStream_t stream) {
  const float* actions = (const float*)d_in[0];
  const float* timesteps = (const float*)d_in[1];
  const float* W1w = (const float*)d_in[2];
  const float* W1b = (const float*)d_in[3];
  const float* W2w = (const float*)d_in[4];
  const float* W2b = (const float*)d_in[5];
  const float* W3w = (const float*)d_in[6];
  const float* W3b = (const float*)d_in[7];
  const int* cats = (const int*)d_in[8];
  float* out = (float*)d_out;

  char* ws = (char*)d_ws;
  __bf16* x2 = (__bf16*)ws;                      // 128*64*2048*2 = 33,554,432 B
  __bf16* h = (__bf16*)(ws + 33554432);          // 128*64*1024*2 = 16,777,216 B
  int* perm = (int*)(ws + 50331648);             // 512 B
  int* wl = (int*)(ws + 50332160);               // 64 slabs * 4 ints = 1024 B
  int* nslab = (int*)(ws + 50333184);            // 4 B

  perm_kernel<<<1, 128, 0, stream>>>(cats, perm, wl, nslab);
  embed_kernel<<<dim3(8, BB), 256, 0, stream>>>(actions, timesteps, W1w, W1b, cats, x2);
  // max slabs = sum ceil(cnt_c/4) <= 32 + 128/4*3/4... bounded by 56; grid.y=64 is safe
  ggemm_kernel<true, true><<<dim3(8, 64), 512, 0, stream>>>(
      x2, W2w, W2b, perm, wl, nslab, (void*)h, 2048);
  ggemm_kernel<false, false><<<dim3(8, 64), 512, 0, stream>>>(
      h, W3w, W3b, perm, wl, nslab, (void*)out, 1024);
}